// Round 8
// baseline (89.803 us; speedup 1.0000x reference)
//
#include <hip/hip_runtime.h>

// RippleLinear: out[b,o] = sum_i amp[i,o] * sin(x[b,i]*freq[i,o] + ph[i,o]) + bias0[o]
//   x:      (2048, 256) f32   (16*128 rows)
//   weight: (256, 256, 2) f32  -> amp = w[i][o][0], freq = w[i][o][1]
//   bias:   (257, 256) f32    -> bias0 = bias[0][:], ph[i][o] = bias[1+i][o]
//   out:    (2048, 256) f32
//
// R7 -> R8: falsified so far: wave count (R6), LDS ops (R5), VALU ops (R7),
// trans pipe (R7 removed v_sin entirely -> flat). The INVARIANT across all
// ~25us rounds is the L2 weight re-stream: 256 row-groups x 768 KB = 201 MB
// -> implied ~8 TB/s effective L2->CU streaming BW is the wall (R3's 402 MB
// -> 57us cross-checks). Fix: BTILE 8->16 halves row-groups -> 98 MB, OSPLIT
// 2->4 keeps grid=512 (2 blk/CU, 16 waves/CU). Also halves VMEM instr count
// (backup suspect: TA issue throughput). Poly sin kept (5 full-rate ops, no
// trans). Block (32 opairs x 16 igroups) = 512 thr; shfl(32) merge + 1-step
// LDS tree (28 KB); x-tile 16 KB transposed, 4-way-conflict staging stores.

constexpr int IN_F   = 256;
constexpr int OUT_F  = 256;
constexpr int BROWS  = 2048;
constexpr int BTILE  = 16;                // batch rows per block
constexpr int ISPLIT = 16;                // i-groups per block
constexpr int ICHUNK = IN_F / ISPLIT;     // 16 i per group
constexpr int OPAIRS = 32;                // o-pairs per block (= 64 o columns)
constexpr int OSPLIT = 4;                 // o-splits across blocks

__device__ __forceinline__ float2 pk_fma(float2 a, float2 b, float2 c) {
    return make_float2(__builtin_fmaf(a.x, b.x, c.x), __builtin_fmaf(a.y, b.y, c.y));
}
__device__ __forceinline__ float2 pk_mul(float2 a, float2 b) {
    return make_float2(a.x * b.x, a.y * b.y);
}

__global__ __launch_bounds__(OPAIRS * ISPLIT, 4) void ripple_kernel(
    const float* __restrict__ x,       // (BROWS, IN_F)
    const float* __restrict__ weight,  // (IN_F, OUT_F, 2)
    const float* __restrict__ bias,    // (IN_F+1, OUT_F)
    float* __restrict__ out)           // (BROWS, OUT_F)
{
    const int tx = threadIdx.x;               // 0..31: o-pair lane
    const int g  = threadIdx.y;               // 0..15: i-group
    const int ob = blockIdx.x & (OSPLIT - 1); // o-quarter
    const int bb = blockIdx.x >> 2;           // row-group
    const int b0 = bb * BTILE;
    const int oc = ob * OPAIRS + tx;          // global o-pair index 0..127

    __shared__ __align__(16) float xs_t[IN_F * BTILE];   // 16 KB, xs_t[i*16+r]
    __shared__ float2 red[ISPLIT / 2 - 1][BTILE][OPAIRS]; // 28 KB

    // --- stage x-tile transposed. Thread t -> (r = t&15, c4 = t>>4):
    //     global: 16 x 64B segments per wave-load (full lines, coalesced);
    //     LDS stores: lane stride 1 float within r -> only 4-way conflict.
    {
        const int t = g * OPAIRS + tx;        // 0..511
        const int r = t & 15;
#pragma unroll
        for (int k = 0; k < 2; ++k) {
            const int c4 = (t >> 4) + 32 * k; // float4 column 0..63
            const float4 v = ((const float4*)x)[(b0 + r) * (IN_F / 4) + c4];
            xs_t[(4 * c4 + 0) * BTILE + r] = v.x;
            xs_t[(4 * c4 + 1) * BTILE + r] = v.y;
            xs_t[(4 * c4 + 2) * BTILE + r] = v.z;
            xs_t[(4 * c4 + 3) * BTILE + r] = v.w;
        }
    }
    __syncthreads();

    float2 acc[BTILE];
#pragma unroll
    for (int r = 0; r < BTILE; ++r) acc[r] = make_float2(0.0f, 0.0f);

    const float4* __restrict__ wq  = (const float4*)weight;  // (amp0,freq0,amp1,freq1)
    const float2* __restrict__ ph2 = (const float2*)bias;    // phase pairs

    // degree-7 odd poly: sin(t) ~= t*(1 + u*(C3 + u*(C5 + u*C7))), u = t^2
    const float2 C7 = make_float2(-1.9841270e-4f, -1.9841270e-4f);
    const float2 C5 = make_float2( 8.3333310e-3f,  8.3333310e-3f);
    const float2 C3 = make_float2(-1.6666667e-1f, -1.6666667e-1f);
    const float2 C1 = make_float2( 1.0f, 1.0f);

    const int i0 = g * ICHUNK;
#pragma unroll 2
    for (int ii = 0; ii < ICHUNK; ++ii) {
        const int i = i0 + ii;
        const float4 w = wq[i * (OUT_F / 2) + oc];           // 16B coalesced
        const float2 p = ph2[(i + 1) * (OUT_F / 2) + oc];    // 8B coalesced
        const float2 amp = make_float2(w.x, w.z);
        const float2 frq = make_float2(w.y, w.w);
        float4 xq[4];
#pragma unroll
        for (int q = 0; q < 4; ++q)
            xq[q] = *(const float4*)&xs_t[i * BTILE + 4 * q]; // broadcast b128
        const float* xv = (const float*)xq;
#pragma unroll
        for (int r = 0; r < BTILE; ++r) {
            const float2 xr = make_float2(xv[r], xv[r]);
            const float2 t  = pk_fma(xr, frq, p);      // arg = x*f + p
            const float2 u  = pk_mul(t, t);
            float2 q        = pk_fma(C7, u, C5);
            q               = pk_fma(q,  u, C3);
            q               = pk_fma(q,  u, C1);
            const float2 s  = pk_mul(t, q);            // sin(arg)
            acc[r]          = pk_fma(amp, s, acc[r]);
        }
    }

    // --- merge the wave's two i-groups (g even/odd pairs) in-register ---
#pragma unroll
    for (int r = 0; r < BTILE; ++r) {
        acc[r].x += __shfl_down(acc[r].x, 32);
        acc[r].y += __shfl_down(acc[r].y, 32);
    }

    // --- one-step LDS reduction across the 8 waves ---
    const int wv = g >> 1;
    if ((g & 1) == 0 && wv > 0) {
#pragma unroll
        for (int r = 0; r < BTILE; ++r) red[wv - 1][r][tx] = acc[r];
    }
    __syncthreads();
    if (g == 0) {                           // lanes 0..31 of wave 0
        const float2 bo = ph2[oc];          // bias row 0
#pragma unroll
        for (int r = 0; r < BTILE; ++r) {
            float s0 = acc[r].x, s1 = acc[r].y;
#pragma unroll
            for (int k = 0; k < ISPLIT / 2 - 1; ++k) {
                const float2 t = red[k][r][tx];
                s0 += t.x; s1 += t.y;
            }
            ((float2*)out)[(b0 + r) * (OUT_F / 2) + oc] = make_float2(s0 + bo.x, s1 + bo.y);
        }
    }
}

extern "C" void kernel_launch(void* const* d_in, const int* in_sizes, int n_in,
                              void* d_out, int out_size, void* d_ws, size_t ws_size,
                              hipStream_t stream) {
    const float* x      = (const float*)d_in[0];
    const float* weight = (const float*)d_in[1];
    const float* bias   = (const float*)d_in[2];
    float* out          = (float*)d_out;

    dim3 grid((BROWS / BTILE) * OSPLIT);   // 512 blocks: 128 row-groups x 4 o-quarters
    dim3 block(OPAIRS, ISPLIT);            // 512 threads = 8 waves
    ripple_kernel<<<grid, block, 0, stream>>>(x, weight, bias, out);
}

// Round 9
// 75.665 us; speedup vs baseline: 1.1868x; 1.1868x over previous
//
#include <hip/hip_runtime.h>

// RippleLinear: out[b,o] = sum_i amp[i,o] * sin(x[b,i]*freq[i,o] + ph[i,o]) + bias0[o]
//   x:      (2048, 256) f32   (16*128 rows)
//   weight: (256, 256, 2) f32  -> amp = w[i][o][0], freq = w[i][o][1]
//   bias:   (257, 256) f32    -> bias0 = bias[0][:], ph[i][o] = bias[1+i][o]
//   out:    (2048, 256) f32
//
// R8 -> R9: R8's counters showed the regression was REGISTER SPILL
// (WRITE_SIZE 18 MB vs 2 MB output; launch_bounds min-waves forced VGPR=64
// under a ~90-reg need) -- the traffic-halving experiment was confounded,
// L2-stream theory still live. R9 re-runs it clean: BTILE 32 (weight
// re-stream 201 -> 49 MB) with per-thread state kept at R5's proven 16
// floats: block = 32 rows x 64 cols, threads (32 opairs x 4 rowsub x 8
// igroups) = 1024, each thread 8 rows x 1 opair x 32 i. v_sin math (R5's,
// empirically faster than poly AND fewer issue slots). No min-waves hint
// (R8's spill trap); 16-wave blocks self-cap VGPR at 128. Grid 256 = 64
// rowgroups x 4 osplits -> 1 block/CU, 16 waves/CU. shfl(32) igroup-pair
// merge + one 24 KB LDS step. LDS 56 KB/block.

constexpr int IN_F   = 256;
constexpr int OUT_F  = 256;
constexpr int BROWS  = 2048;
constexpr int BTILE  = 32;                // rows per block
constexpr int RSUB   = 4;                 // row subgroups per block
constexpr int RPT    = 8;                 // rows per thread
constexpr int IGRP   = 8;                 // i-groups per block
constexpr int ICHUNK = IN_F / IGRP;       // 32 i per group
constexpr int OPAIRS = 32;                // o-pairs per block (= 64 cols)
constexpr int OSPLIT = 4;                 // o-splits across blocks

#define INV2PI 0.15915494309189535f

__global__ __launch_bounds__(1024) void ripple_kernel(
    const float* __restrict__ x,       // (BROWS, IN_F)
    const float* __restrict__ weight,  // (IN_F, OUT_F, 2)
    const float* __restrict__ bias,    // (IN_F+1, OUT_F)
    float* __restrict__ out)           // (BROWS, OUT_F)
{
    const int tx = threadIdx.x;               // 0..31: o-pair lane
    const int y  = threadIdx.y;               // 0..31
    const int ig = y & 7;                     // i-group 0..7
    const int rs = y >> 3;                    // row subgroup 0..3
    const int ob = blockIdx.x & (OSPLIT - 1); // o-quarter
    const int bb = blockIdx.x >> 2;           // row-group
    const int b0 = bb * BTILE;
    const int oc = ob * OPAIRS + tx;          // global o-pair 0..127

    // wave layout: lane = tx + 32*(y&1); a wave holds y = {2w, 2w+1} =
    // i-groups {2g, 2g+1} of the SAME row subgroup -> shfl(32) merges pairs.

    __shared__ __align__(16) float xs_t[IN_F * BTILE];   // 32 KB, xs_t[i*32+r] = x/(2pi)
    __shared__ float2 red[3][RSUB][RPT][OPAIRS];         // 24 KB

    // --- stage x-tile transposed+prescaled ---
    // thread t -> (r = t&31, c4 = t>>5): LDS stores conflict-free
    // (consecutive lanes -> consecutive floats); global reads are 16B/lane
    // one-time (8 MB total across grid, L2-resident).
    {
        const int t  = tx + 32 * y;           // 0..1023
        const int r  = t & 31;
        const int c4 = t >> 5;                // float4 column 0..31
#pragma unroll
        for (int k = 0; k < 2; ++k) {
            const int c = c4 + 32 * k;
            const float4 v = ((const float4*)x)[(b0 + r) * (IN_F / 4) + c];
            xs_t[(4 * c + 0) * BTILE + r] = v.x * INV2PI;
            xs_t[(4 * c + 1) * BTILE + r] = v.y * INV2PI;
            xs_t[(4 * c + 2) * BTILE + r] = v.z * INV2PI;
            xs_t[(4 * c + 3) * BTILE + r] = v.w * INV2PI;
        }
    }
    __syncthreads();

    float2 acc[RPT];
#pragma unroll
    for (int r = 0; r < RPT; ++r) acc[r] = make_float2(0.0f, 0.0f);

    const float4* __restrict__ wq  = (const float4*)weight;  // (amp0,freq0,amp1,freq1)
    const float2* __restrict__ ph2 = (const float2*)bias;    // phase pairs

    const int i0 = ig * ICHUNK;
    const int r0 = rs * RPT;
#pragma unroll 4
    for (int ii = 0; ii < ICHUNK; ++ii) {
        const int i = i0 + ii;
        const float4 w = wq[i * (OUT_F / 2) + oc];           // 512B/half-wave
        const float2 p = ph2[(i + 1) * (OUT_F / 2) + oc];    // 256B/half-wave
        const float px = p.x * INV2PI;
        const float py = p.y * INV2PI;
        const float4 xa = *(const float4*)&xs_t[i * BTILE + r0];      // b128 broadcast
        const float4 xb = *(const float4*)&xs_t[i * BTILE + r0 + 4];  // b128 broadcast
        const float xv[RPT] = {xa.x, xa.y, xa.z, xa.w, xb.x, xb.y, xb.z, xb.w};
#pragma unroll
        for (int r = 0; r < RPT; ++r) {
            acc[r].x += w.x * __builtin_amdgcn_sinf(fmaf(xv[r], w.y, px));
            acc[r].y += w.z * __builtin_amdgcn_sinf(fmaf(xv[r], w.w, py));
        }
    }

    // --- merge i-group pairs within each wave (lanes 0-31 <- lanes 32-63) ---
#pragma unroll
    for (int r = 0; r < RPT; ++r) {
        acc[r].x += __shfl_down(acc[r].x, 32);
        acc[r].y += __shfl_down(acc[r].y, 32);
    }

    // --- one LDS step across the 4 i-group pairs ---
    const int pg = ig >> 1;                   // pair index 0..3 (valid when ig even)
    if ((ig & 1) == 0 && pg > 0) {
#pragma unroll
        for (int r = 0; r < RPT; ++r) red[pg - 1][rs][r][tx] = acc[r];
    }
    __syncthreads();
    if (ig == 0) {
        const float2 bo = ph2[oc];            // bias row 0 (unscaled)
#pragma unroll
        for (int r = 0; r < RPT; ++r) {
            float sx = acc[r].x, sy = acc[r].y;
#pragma unroll
            for (int k = 0; k < 3; ++k) {
                const float2 t = red[k][rs][r][tx];
                sx += t.x; sy += t.y;
            }
            ((float2*)out)[(b0 + r0 + r) * (OUT_F / 2) + oc] =
                make_float2(sx + bo.x, sy + bo.y);
        }
    }
}

extern "C" void kernel_launch(void* const* d_in, const int* in_sizes, int n_in,
                              void* d_out, int out_size, void* d_ws, size_t ws_size,
                              hipStream_t stream) {
    const float* x      = (const float*)d_in[0];
    const float* weight = (const float*)d_in[1];
    const float* bias   = (const float*)d_in[2];
    float* out          = (float*)d_out;

    dim3 grid((BROWS / BTILE) * OSPLIT);   // 256 blocks: 64 row-groups x 4 o-quarters
    dim3 block(OPAIRS, BTILE);             // (32, 32) = 1024 threads = 16 waves
    ripple_kernel<<<grid, block, 0, stream>>>(x, weight, bias, out);
}